// Round 18
// baseline (203.406 us; speedup 1.0000x reference)
//
#include <hip/hip_runtime.h>
#include <hip/hip_fp16.h>

typedef _Float16 f16x8 __attribute__((ext_vector_type(8)));
typedef float f32x16 __attribute__((ext_vector_type(16)));

// LeNet C3 connection table: input channel ii feeds CONN[ii][j] with weight[j][ii].
__device__ constexpr int CONN[6][10] = {
    {0, 4, 5, 6, 9, 10, 11, 12, 14, 15},
    {0, 1, 5, 6, 7, 10, 11, 12, 13, 15},
    {0, 1, 2, 6, 7, 8, 11, 13, 14, 15},
    {1, 2, 3, 6, 7, 8, 9, 12, 14, 15},
    {2, 3, 4, 7, 8, 9, 10, 12, 13, 15},
    {3, 4, 5, 8, 9, 10, 11, 13, 14, 15}};

__device__ constexpr int CNT[16] = {3,3,3,3,3,3,4,4,4,4,4,4,4,4,4,6};

__device__ __forceinline__ f16x8 u4_to_h8(uint4 u) { f16x8 r; __builtin_memcpy(&r, &u, 16); return r; }

#define PITCH_DW 132            // 264 halves/row: 256 data + 8 zero halo
#define PLANE_DW 2128           // 16*132 + 16 pad; == 16 mod 32 (kb bank split)
#define LDS_DW   (6 * 2128 + 140)

// A-panel for mfma_f32_32x32x16_f16, M=32 (rows 16..31 zero), 15 MFMAs:
// slice = ms + 15*kb; ii = slice/5; r = slice%5;
// Wp[(ms*64+lane)*8+j] = (ch<16 && j<5) ? w_full[ch][ii][r][j] : 0
__global__ void prep_A(const float* __restrict__ w, unsigned short* __restrict__ Wp) {
    int t = blockIdx.x * 256 + threadIdx.x;   // half index 0..7679
    if (t >= 7680) return;
    int j = t & 7, lane = (t >> 3) & 63, ms = t >> 9;
    int ch = lane & 31, kb = lane >> 5;
    int slice = ms + 15 * kb;
    int ii = slice / 5, r = slice % 5;
    float val = 0.f;
    if (ch < 16 && j < 5)
        for (int jj = 0; jj < 10; ++jj)
            if (CONN[ii][jj] == ch) val = w[jj * 150 + ii * 25 + r * 5 + j];
    __half h = __float2half(val);
    unsigned short u; __builtin_memcpy(&u, &h, 2);
    Wp[t] = u;
}

// Block: 256x x 12y tile, 4 waves, each wave owns TWO resident 32-x strips
// (lo: x=32wv+nn, hi: x=128+32wv+nn). Per y-phase the block writes ALL 252 x
// of each (ch,y) output row (clean page-ordered write stream, R16-verified).
// R18 delta vs R15: each strip's 15-MFMA chain split into TWO independent
// chains (8+7) summed at store -> halved exposed MFMA dependency latency.
__global__ __launch_bounds__(256, 2) void c3_mfma(
    const float* __restrict__ x, const unsigned short* __restrict__ Wp,
    const float* __restrict__ bias, float* __restrict__ out)
{
    __shared__ unsigned s_lds[LDS_DW];   // 51632 B

    const int tid = threadIdx.x;
    // 1344 blocks = 64 n x 21 y-tiles; bijective XCD chunking (1344 = 8*168).
    const int id = (blockIdx.x & 7) * 168 + (blockIdx.x >> 3);
    const int by = id % 21;
    const int n  = id / 21;
    const int Y0 = by * 12;
    const float* xin = x + (size_t)n * 6 * 65536;

    // ---- stage 6ch x 16row x 256col f32 -> fp16 (pow2 indices, no guards) ----
    #pragma unroll 4
    for (int it = 0; it < 24; ++it) {
        int i   = tid + it * 256;          // 0..6143
        int c4  = i & 63;
        int row = (i >> 6) & 15;
        int ch  = i >> 10;
        float4 v = *reinterpret_cast<const float4*>(
            xin + (size_t)ch * 65536 + (size_t)(Y0 + row) * 256 + c4 * 4);
        __half2 lo = __floats2half2_rn(v.x, v.y);
        __half2 hi = __floats2half2_rn(v.z, v.w);
        uint2 u; __builtin_memcpy(&u.x, &lo, 4); __builtin_memcpy(&u.y, &hi, 4);
        *reinterpret_cast<uint2*>(&s_lds[ch * PLANE_DW + row * PITCH_DW + c4 * 2]) = u;
    }
    // halo halves 256..263 = zero
    if (tid < 96) {
        int ch = tid >> 4, row = tid & 15;
        *reinterpret_cast<uint4*>(&s_lds[ch * PLANE_DW + row * PITCH_DW + 128]) =
            make_uint4(0u, 0u, 0u, 0u);
    }
    __syncthreads();

    const int lane = tid & 63;
    const int wv   = tid >> 6;
    const int nn   = lane & 31;    // B-col = x; C-col = x
    const int kb   = lane >> 5;    // plane-half selector; C rows += 4*kb

    // ---- weight A-frags (15 x 16B, L2-hot) ----
    f16x8 W[15];
    const uint4* wp4 = reinterpret_cast<const uint4*>(Wp);
    #pragma unroll
    for (int ms = 0; ms < 15; ++ms) W[ms] = u4_to_h8(wp4[ms * 64 + lane]);

    // ---- C init: regs 0..7 = bias for ch=(reg&3)+8*(reg>>2)+4*kb; 8..15 = 0 ----
    f32x16 cinit, z16;
    #pragma unroll
    for (int reg = 0; reg < 8; ++reg) {
        int ch = (reg & 3) + 8 * (reg >> 2) + 4 * kb;
        cinit[reg] = bias[ch] * (float)CNT[ch];
    }
    #pragma unroll
    for (int reg = 8; reg < 16; ++reg) cinit[reg] = 0.f;
    #pragma unroll
    for (int reg = 0; reg < 16; ++reg) z16[reg] = 0.f;

    const int gxL = 32 * wv + nn;              // always < 252
    const int gxH = 128 + 32 * wv + nn;        // may exceed 251
    const bool okH = gxH < 252;
    const int pbL = 3 * kb * PLANE_DW + (gxL >> 1);
    const int pbH = 3 * kb * PLANE_DW + (gxH >> 1);
    const bool oddL = (gxL >> 1) & 1;
    const bool oddH = (gxH >> 1) & 1;
    const unsigned shb = (unsigned)((nn & 1) * 16);

    auto loadf = [&](int dw, bool odd) -> f16x8 {
        int d0 = dw & ~1;
        uint2 r0 = *reinterpret_cast<const uint2*>(&s_lds[d0]);
        uint2 r1 = *reinterpret_cast<const uint2*>(&s_lds[d0 + 2]);
        uint2 r2 = *reinterpret_cast<const uint2*>(&s_lds[d0 + 4]);
        unsigned e0 = odd ? r0.y : r0.x;
        unsigned e1 = odd ? r1.x : r0.y;
        unsigned e2 = odd ? r1.y : r1.x;
        unsigned e3 = odd ? r2.x : r1.y;
        unsigned e4 = odd ? r2.y : r2.x;
        unsigned o0 = (unsigned)((((unsigned long long)e1 << 32) | e0) >> shb);
        unsigned o1 = (unsigned)((((unsigned long long)e2 << 32) | e1) >> shb);
        unsigned o2 = (unsigned)((((unsigned long long)e3 << 32) | e2) >> shb);
        unsigned o3 = (unsigned)((((unsigned long long)e4 << 32) | e3) >> shb);
        return u4_to_h8(make_uint4(o0, o1, o2, o3));
    };

    // prologue: rows 0..4 x 3 planes x 2 strips
    f16x8 L00 = loadf(pbL + 0*PITCH_DW, oddL), L01 = loadf(pbL + 1*PITCH_DW, oddL),
          L02 = loadf(pbL + 2*PITCH_DW, oddL), L03 = loadf(pbL + 3*PITCH_DW, oddL),
          L04 = loadf(pbL + 4*PITCH_DW, oddL);
    f16x8 L10 = loadf(pbL + PLANE_DW + 0*PITCH_DW, oddL), L11 = loadf(pbL + PLANE_DW + 1*PITCH_DW, oddL),
          L12 = loadf(pbL + PLANE_DW + 2*PITCH_DW, oddL), L13 = loadf(pbL + PLANE_DW + 3*PITCH_DW, oddL),
          L14 = loadf(pbL + PLANE_DW + 4*PITCH_DW, oddL);
    f16x8 L20 = loadf(pbL + 2*PLANE_DW + 0*PITCH_DW, oddL), L21 = loadf(pbL + 2*PLANE_DW + 1*PITCH_DW, oddL),
          L22 = loadf(pbL + 2*PLANE_DW + 2*PITCH_DW, oddL), L23 = loadf(pbL + 2*PLANE_DW + 3*PITCH_DW, oddL),
          L24 = loadf(pbL + 2*PLANE_DW + 4*PITCH_DW, oddL);
    f16x8 H00 = loadf(pbH + 0*PITCH_DW, oddH), H01 = loadf(pbH + 1*PITCH_DW, oddH),
          H02 = loadf(pbH + 2*PITCH_DW, oddH), H03 = loadf(pbH + 3*PITCH_DW, oddH),
          H04 = loadf(pbH + 4*PITCH_DW, oddH);
    f16x8 H10 = loadf(pbH + PLANE_DW + 0*PITCH_DW, oddH), H11 = loadf(pbH + PLANE_DW + 1*PITCH_DW, oddH),
          H12 = loadf(pbH + PLANE_DW + 2*PITCH_DW, oddH), H13 = loadf(pbH + PLANE_DW + 3*PITCH_DW, oddH),
          H14 = loadf(pbH + PLANE_DW + 4*PITCH_DW, oddH);
    f16x8 H20 = loadf(pbH + 2*PLANE_DW + 0*PITCH_DW, oddH), H21 = loadf(pbH + 2*PLANE_DW + 1*PITCH_DW, oddH),
          H22 = loadf(pbH + 2*PLANE_DW + 2*PITCH_DW, oddH), H23 = loadf(pbH + 2*PLANE_DW + 3*PITCH_DW, oddH),
          H24 = loadf(pbH + 2*PLANE_DW + 4*PITCH_DW, oddH);
    int rowOff = 5 * PITCH_DW;

    float* const opL = out + (size_t)n * 16 * 63504 + (size_t)(4 * kb) * 63504 + gxL;
    float* const opH = out + (size_t)n * 16 * 63504 + (size_t)(4 * kb) * 63504 + gxH;
    int yoff = Y0 * 252;

#define MFMA32(a, b, c) __builtin_amdgcn_mfma_f32_32x32x16_f16(a, b, c, 0, 0, 0)

// Two independent chains (8 + 7), interleaved; summed at store.
#define STRIP(f00,f01,f02,f03,f04, f10,f11,f12,f13,f14, f20,f21,f22,f23,f24, pb, od, opg, ok) \
    {                                                                          \
        f32x16 accA = cinit, accB = z16;                                       \
        accA = MFMA32(W[0],  f00, accA);  accB = MFMA32(W[8],  f13, accB);     \
        accA = MFMA32(W[1],  f01, accA);  accB = MFMA32(W[9],  f14, accB);     \
        accA = MFMA32(W[2],  f02, accA);  accB = MFMA32(W[10], f20, accB);     \
        accA = MFMA32(W[3],  f03, accA);  accB = MFMA32(W[11], f21, accB);     \
        accA = MFMA32(W[4],  f04, accA);  accB = MFMA32(W[12], f22, accB);     \
        accA = MFMA32(W[5],  f10, accA);  accB = MFMA32(W[13], f23, accB);     \
        accA = MFMA32(W[6],  f11, accA);  accB = MFMA32(W[14], f24, accB);     \
        accA = MFMA32(W[7],  f12, accA);                                       \
        if (ok) {                                                              \
            opg[yoff +  0 * 63504] = accA[0] + accB[0];                        \
            opg[yoff +  1 * 63504] = accA[1] + accB[1];                        \
            opg[yoff +  2 * 63504] = accA[2] + accB[2];                        \
            opg[yoff +  3 * 63504] = accA[3] + accB[3];                        \
            opg[yoff +  8 * 63504] = accA[4] + accB[4];                        \
            opg[yoff +  9 * 63504] = accA[5] + accB[5];                        \
            opg[yoff + 10 * 63504] = accA[6] + accB[6];                        \
            opg[yoff + 11 * 63504] = accA[7] + accB[7];                        \
        }                                                                      \
        f00 = loadf(pb + rowOff, od);                                          \
        f10 = loadf(pb + PLANE_DW + rowOff, od);                               \
        f20 = loadf(pb + 2 * PLANE_DW + rowOff, od);                           \
    }

#define PHASE(r0,r1,r2,r3,r4)                                                          \
    STRIP(L0##r0,L0##r1,L0##r2,L0##r3,L0##r4, L1##r0,L1##r1,L1##r2,L1##r3,L1##r4,      \
          L2##r0,L2##r1,L2##r2,L2##r3,L2##r4, pbL, oddL, opL, true)                    \
    STRIP(H0##r0,H0##r1,H0##r2,H0##r3,H0##r4, H1##r0,H1##r1,H1##r2,H1##r3,H1##r4,      \
          H2##r0,H2##r1,H2##r2,H2##r3,H2##r4, pbH, oddH, opH, okH)                     \
    rowOff += PITCH_DW; yoff += 252;

    PHASE(0,1,2,3,4)
    PHASE(1,2,3,4,0)
    PHASE(2,3,4,0,1)
    PHASE(3,4,0,1,2)
    PHASE(4,0,1,2,3)
    PHASE(0,1,2,3,4)
    PHASE(1,2,3,4,0)
    PHASE(2,3,4,0,1)
    PHASE(3,4,0,1,2)
    PHASE(4,0,1,2,3)
    PHASE(0,1,2,3,4)
    PHASE(1,2,3,4,0)
#undef PHASE
#undef STRIP
#undef MFMA32
}

extern "C" void kernel_launch(void* const* d_in, const int* in_sizes, int n_in,
                              void* d_out, int out_size, void* d_ws, size_t ws_size,
                              hipStream_t stream) {
    const float* x    = (const float*)d_in[0];  // (64,6,256,256)
    const float* w    = (const float*)d_in[1];  // (10,6,5,5)
    const float* bias = (const float*)d_in[2];  // (1,16,1,1)
    float* out = (float*)d_out;                 // (64,16,252,252)
    unsigned short* Wp = (unsigned short*)d_ws; // 7680 halves (15 KB) A panel

    hipLaunchKernelGGL(prep_A, dim3(30), dim3(256), 0, stream, w, Wp);
    hipLaunchKernelGGL(c3_mfma, dim3(1344), dim3(256), 0, stream, x, Wp, bias, out);
}

// Round 19
// 133.653 us; speedup vs baseline: 1.5219x; 1.5219x over previous
//
#include <hip/hip_runtime.h>
#include <hip/hip_fp16.h>

typedef _Float16 f16x8 __attribute__((ext_vector_type(8)));
typedef float f32x4 __attribute__((ext_vector_type(4)));

// LeNet C3 connection table: input channel ii feeds CONN[ii][j] with weight[j][ii].
__device__ constexpr int CONN[6][10] = {
    {0, 4, 5, 6, 9, 10, 11, 12, 14, 15},
    {0, 1, 5, 6, 7, 10, 11, 12, 13, 15},
    {0, 1, 2, 6, 7, 8, 11, 13, 14, 15},
    {1, 2, 3, 6, 7, 8, 9, 12, 14, 15},
    {2, 3, 4, 7, 8, 9, 10, 12, 13, 15},
    {3, 4, 5, 8, 9, 10, 11, 13, 14, 15}};

__device__ constexpr int CNT[16] = {3,3,3,3,3,3,4,4,4,4,4,4,4,4,4,6};

__device__ __forceinline__ f16x8 u4_to_h8(uint4 u) { f16x8 r; __builtin_memcpy(&r, &u, 16); return r; }

#define PITCH_DW 128            // pow2 pitch, no halo (wrap feeds only zero-weight j>=5 / masked x>=252)
#define PLANE_DW 2048           // 16 rows x 128 dw
#define PANEL_DW 12288          // 6 planes; panel (2560 dw) follows
#define LDS_DW   14848          // 59392 B -> 1 block/CU (VGPR-limited anyway)

// Block: 1024 threads = 16 waves; wave wv owns x-strip [16wv, 16wv+15].
// Per y-phase the block writes ALL 252 x of each (ch,y) page (clean write
// stream, R16-verified) with ZERO main-loop barriers (waves free-run after
// staging). Per-wave structure = R11's proven 16x16x32 path (~120 VGPR), so
// 4 waves/SIMD (50% occupancy) fit under the 128-VGPR cap — 2x R15's
// latency-hiding at R15's traffic quality.
__global__ __launch_bounds__(1024, 4) void c3_mfma(
    const float* __restrict__ x, const float* __restrict__ w,
    const float* __restrict__ bias, float* __restrict__ out)
{
    __shared__ unsigned s_lds[LDS_DW];
    unsigned short* s_panel = reinterpret_cast<unsigned short*>(s_lds + PANEL_DW);

    const int tid = threadIdx.x;
    // 1344 blocks = 64 n x 21 y-tiles; bijective XCD chunking (1344 = 8*168).
    const int id = (blockIdx.x & 7) * 168 + (blockIdx.x >> 3);
    const int by = id % 21;
    const int n  = id / 21;
    const int Y0 = by * 12;                 // stage rows Y0..Y0+15 (max 255, no guards)
    const float* xin = x + (size_t)n * 6 * 65536;

    // ---- build weight A-panel in LDS (16x16x32, M=16 ch, K'=320, 10 MFMAs):
    // ks 0..4: ii=2*kb, r=ks (range A); ks 5..9: ii=2*kb+1, r=ks-5 (range B)
    // panel[(ks*64+lane)*8+j] = (kb<3 && j<5) ? w_full[ch=lane&15][ii][r][j] : 0
    for (int t = tid; t < 5120; t += 1024) {
        int j = t & 7, lane = (t >> 3) & 63, ks = t >> 9;
        int ch = lane & 15, kb = lane >> 4;
        float val = 0.f;
        if (kb < 3 && j < 5) {
            int ii = 2 * kb + (ks >= 5 ? 1 : 0);
            int r  = (ks >= 5) ? ks - 5 : ks;
            for (int jj = 0; jj < 10; ++jj)
                if (CONN[ii][jj] == ch) val = w[jj * 150 + ii * 25 + r * 5 + j];
        }
        __half h = __float2half(val);
        unsigned short u; __builtin_memcpy(&u, &h, 2);
        s_panel[t] = u;
    }

    // ---- stage 6ch x 16row x 256col f32 -> fp16 (pow2 indices, no guards) ----
    #pragma unroll
    for (int it = 0; it < 6; ++it) {
        int i   = tid + it * 1024;         // 0..6143
        int c4  = i & 63;
        int row = (i >> 6) & 15;
        int ch  = i >> 10;
        float4 v = *reinterpret_cast<const float4*>(
            xin + (size_t)ch * 65536 + (size_t)(Y0 + row) * 256 + c4 * 4);
        __half2 lo = __floats2half2_rn(v.x, v.y);
        __half2 hi = __floats2half2_rn(v.z, v.w);
        uint2 u; __builtin_memcpy(&u.x, &lo, 4); __builtin_memcpy(&u.y, &hi, 4);
        *reinterpret_cast<uint2*>(&s_lds[ch * PLANE_DW + row * PITCH_DW + c4 * 2]) = u;
    }
    __syncthreads();

    const int lane = tid & 63;
    const int wv   = tid >> 6;     // 16 waves: strip x = [16wv, 16wv+15]
    const int nn   = lane & 15;    // B-col = x; C-col = x
    const int kb   = lane >> 4;    // k-block; C rows = ch = kb*4+q

    // ---- weight A-frags from LDS panel (10 x 16B) ----
    f16x8 W[10];
    {
        const uint4* p4 = reinterpret_cast<const uint4*>(s_panel);
        #pragma unroll
        for (int ks = 0; ks < 10; ++ks) W[ks] = u4_to_h8(p4[ks * 64 + lane]);
    }

    const int iiA = (kb < 3) ? 2 * kb : 0;             // kb3: dummy (zero weights)
    const int gx  = 16 * wv + nn;                      // 0..255
    const bool ok = gx < 252;
    const int pb  = iiA * PLANE_DW + (gx >> 1);
    const unsigned shb = (unsigned)((gx & 1) * 16);    // 16-bit funnel shift

    auto loadf = [&](int dw) -> f16x8 {
        unsigned e0 = s_lds[dw],     e1 = s_lds[dw + 1],
                 e2 = s_lds[dw + 2], e3 = s_lds[dw + 3],
                 e4 = s_lds[dw + 4];
        unsigned o0 = (unsigned)((((unsigned long long)e1 << 32) | e0) >> shb);
        unsigned o1 = (unsigned)((((unsigned long long)e2 << 32) | e1) >> shb);
        unsigned o2 = (unsigned)((((unsigned long long)e3 << 32) | e2) >> shb);
        unsigned o3 = (unsigned)((((unsigned long long)e4 << 32) | e3) >> shb);
        return u4_to_h8(make_uint4(o0, o1, o2, o3));
    };

    float bb[4];
    #pragma unroll
    for (int q = 0; q < 4; ++q) {
        int ch = kb * 4 + q;
        bb[q] = bias[ch] * (float)CNT[ch];
    }

    // prologue: rows 0..4 of ranges A (plane iiA) and B (plane iiA+1)
    f16x8 A0 = loadf(pb + 0 * PITCH_DW), A1 = loadf(pb + 1 * PITCH_DW),
          A2 = loadf(pb + 2 * PITCH_DW), A3 = loadf(pb + 3 * PITCH_DW),
          A4 = loadf(pb + 4 * PITCH_DW);
    f16x8 B0 = loadf(pb + PLANE_DW + 0 * PITCH_DW), B1 = loadf(pb + PLANE_DW + 1 * PITCH_DW),
          B2 = loadf(pb + PLANE_DW + 2 * PITCH_DW), B3 = loadf(pb + PLANE_DW + 3 * PITCH_DW),
          B4 = loadf(pb + PLANE_DW + 4 * PITCH_DW);
    int aN = pb + 5 * PITCH_DW;

    float* const op0 = out + (size_t)n * 16 * 63504 + (size_t)(kb * 4) * 63504 + gx;
    int yoff = Y0 * 252;

#define PHASE(a0,a1,a2,a3,a4,b0,b1,b2,b3,b4)                                    \
    {                                                                           \
        f32x4 accA = {bb[0], bb[1], bb[2], bb[3]};                              \
        f32x4 accB = {0.f, 0.f, 0.f, 0.f};                                      \
        accA = __builtin_amdgcn_mfma_f32_16x16x32_f16(W[0], a0, accA, 0, 0, 0); \
        accB = __builtin_amdgcn_mfma_f32_16x16x32_f16(W[5], b0, accB, 0, 0, 0); \
        a0 = loadf(aN); b0 = loadf(aN + PLANE_DW); aN += PITCH_DW;              \
        accA = __builtin_amdgcn_mfma_f32_16x16x32_f16(W[1], a1, accA, 0, 0, 0); \
        accB = __builtin_amdgcn_mfma_f32_16x16x32_f16(W[6], b1, accB, 0, 0, 0); \
        accA = __builtin_amdgcn_mfma_f32_16x16x32_f16(W[2], a2, accA, 0, 0, 0); \
        accB = __builtin_amdgcn_mfma_f32_16x16x32_f16(W[7], b2, accB, 0, 0, 0); \
        accA = __builtin_amdgcn_mfma_f32_16x16x32_f16(W[3], a3, accA, 0, 0, 0); \
        accB = __builtin_amdgcn_mfma_f32_16x16x32_f16(W[8], b3, accB, 0, 0, 0); \
        accA = __builtin_amdgcn_mfma_f32_16x16x32_f16(W[4], a4, accA, 0, 0, 0); \
        accB = __builtin_amdgcn_mfma_f32_16x16x32_f16(W[9], b4, accB, 0, 0, 0); \
        if (ok) {                                                               \
            f32x4 acc = accA + accB;                                            \
            op0[0 * 63504 + yoff] = acc[0];                                     \
            op0[1 * 63504 + yoff] = acc[1];                                     \
            op0[2 * 63504 + yoff] = acc[2];                                     \
            op0[3 * 63504 + yoff] = acc[3];                                     \
        }                                                                       \
        yoff += 252;                                                            \
    }
    // last phase's rolling reload reads the next plane's row 0 / panel region:
    // in-bounds, garbage, unused.

    PHASE(A0, A1, A2, A3, A4, B0, B1, B2, B3, B4)
    PHASE(A1, A2, A3, A4, A0, B1, B2, B3, B4, B0)
    PHASE(A2, A3, A4, A0, A1, B2, B3, B4, B0, B1)
    PHASE(A3, A4, A0, A1, A2, B3, B4, B0, B1, B2)
    PHASE(A4, A0, A1, A2, A3, B4, B0, B1, B2, B3)
    PHASE(A0, A1, A2, A3, A4, B0, B1, B2, B3, B4)
    PHASE(A1, A2, A3, A4, A0, B1, B2, B3, B4, B0)
    PHASE(A2, A3, A4, A0, A1, B2, B3, B4, B0, B1)
    PHASE(A3, A4, A0, A1, A2, B3, B4, B0, B1, B2)
    PHASE(A4, A0, A1, A2, A3, B4, B0, B1, B2, B3)
    PHASE(A0, A1, A2, A3, A4, B0, B1, B2, B3, B4)
    PHASE(A1, A2, A3, A4, A0, B1, B2, B3, B4, B0)
#undef PHASE
}

extern "C" void kernel_launch(void* const* d_in, const int* in_sizes, int n_in,
                              void* d_out, int out_size, void* d_ws, size_t ws_size,
                              hipStream_t stream) {
    const float* x    = (const float*)d_in[0];  // (64,6,256,256)
    const float* w    = (const float*)d_in[1];  // (10,6,5,5)
    const float* bias = (const float*)d_in[2];  // (1,16,1,1)
    float* out = (float*)d_out;                 // (64,16,252,252)

    hipLaunchKernelGGL(c3_mfma, dim3(1344), dim3(1024), 0, stream, x, w, bias, out);
}

// Round 20
// 105.012 us; speedup vs baseline: 1.9370x; 1.2727x over previous
//
#include <hip/hip_runtime.h>
#include <hip/hip_fp16.h>

typedef _Float16 f16x8 __attribute__((ext_vector_type(8)));
typedef float f32x16 __attribute__((ext_vector_type(16)));

// LeNet C3 connection table: input channel ii feeds CONN[ii][j] with weight[j][ii].
__device__ constexpr int CONN[6][10] = {
    {0, 4, 5, 6, 9, 10, 11, 12, 14, 15},
    {0, 1, 5, 6, 7, 10, 11, 12, 13, 15},
    {0, 1, 2, 6, 7, 8, 11, 13, 14, 15},
    {1, 2, 3, 6, 7, 8, 9, 12, 14, 15},
    {2, 3, 4, 7, 8, 9, 10, 12, 13, 15},
    {3, 4, 5, 8, 9, 10, 11, 13, 14, 15}};

__device__ constexpr int CNT[16] = {3,3,3,3,3,3,4,4,4,4,4,4,4,4,4,6};

__device__ __forceinline__ f16x8 u4_to_h8(uint4 u) { f16x8 r; __builtin_memcpy(&r, &u, 16); return r; }

#define PITCH_DW 132            // 264 halves/row: 256 data + 8 zero halo
#define PLANE_DW 2128           // 16*132 + 16 pad; == 16 mod 32 (kb bank split)
#define LDS_DW   (6 * 2128 + 140)

// A-panel for mfma_f32_32x32x16_f16, M=32 (rows 16..31 zero), 15 MFMAs:
// slice = ms + 15*kb; ii = slice/5; r = slice%5;
// Wp[(ms*64+lane)*8+j] = (ch<16 && j<5) ? w_full[ch][ii][r][j] : 0
__global__ void prep_A(const float* __restrict__ w, unsigned short* __restrict__ Wp) {
    int t = blockIdx.x * 256 + threadIdx.x;   // half index 0..7679
    if (t >= 7680) return;
    int j = t & 7, lane = (t >> 3) & 63, ms = t >> 9;
    int ch = lane & 31, kb = lane >> 5;
    int slice = ms + 15 * kb;
    int ii = slice / 5, r = slice % 5;
    float val = 0.f;
    if (ch < 16 && j < 5)
        for (int jj = 0; jj < 10; ++jj)
            if (CONN[ii][jj] == ch) val = w[jj * 150 + ii * 25 + r * 5 + j];
    __half h = __float2half(val);
    unsigned short u; __builtin_memcpy(&u, &h, 2);
    Wp[t] = u;
}

// Block: 256x x 12y tile, 4 waves, each wave owns TWO resident 32-x strips
// (lo: x=32wv+nn, hi: x=128+32wv+nn). Per y-phase the block writes ALL 252 x
// of each (ch,y) output row -> each ~1KB DRAM page opened once (fill-like
// write stream; kills the 4-visit page thrash of the R11 strip loop).
__global__ __launch_bounds__(256, 2) void c3_mfma(
    const float* __restrict__ x, const unsigned short* __restrict__ Wp,
    const float* __restrict__ bias, float* __restrict__ out)
{
    __shared__ unsigned s_lds[LDS_DW];   // 51632 B

    const int tid = threadIdx.x;
    // 1344 blocks = 64 n x 21 y-tiles; bijective XCD chunking (1344 = 8*168).
    const int id = (blockIdx.x & 7) * 168 + (blockIdx.x >> 3);
    const int by = id % 21;
    const int n  = id / 21;
    const int Y0 = by * 12;
    const float* xin = x + (size_t)n * 6 * 65536;

    // ---- stage 6ch x 16row x 256col f32 -> fp16 (pow2 indices, no guards) ----
    #pragma unroll 4
    for (int it = 0; it < 24; ++it) {
        int i   = tid + it * 256;          // 0..6143
        int c4  = i & 63;
        int row = (i >> 6) & 15;
        int ch  = i >> 10;
        float4 v = *reinterpret_cast<const float4*>(
            xin + (size_t)ch * 65536 + (size_t)(Y0 + row) * 256 + c4 * 4);
        __half2 lo = __floats2half2_rn(v.x, v.y);
        __half2 hi = __floats2half2_rn(v.z, v.w);
        uint2 u; __builtin_memcpy(&u.x, &lo, 4); __builtin_memcpy(&u.y, &hi, 4);
        *reinterpret_cast<uint2*>(&s_lds[ch * PLANE_DW + row * PITCH_DW + c4 * 2]) = u;
    }
    // halo halves 256..263 = zero
    if (tid < 96) {
        int ch = tid >> 4, row = tid & 15;
        *reinterpret_cast<uint4*>(&s_lds[ch * PLANE_DW + row * PITCH_DW + 128]) =
            make_uint4(0u, 0u, 0u, 0u);
    }
    __syncthreads();

    const int lane = tid & 63;
    const int wv   = tid >> 6;
    const int nn   = lane & 31;    // B-col = x; C-col = x
    const int kb   = lane >> 5;    // plane-half selector; C rows += 4*kb

    // ---- weight A-frags (15 x 16B, L2-hot) ----
    f16x8 W[15];
    const uint4* wp4 = reinterpret_cast<const uint4*>(Wp);
    #pragma unroll
    for (int ms = 0; ms < 15; ++ms) W[ms] = u4_to_h8(wp4[ms * 64 + lane]);

    // ---- C init: regs 0..7 = bias for ch=(reg&3)+8*(reg>>2)+4*kb; 8..15 = 0 ----
    f32x16 cinit;
    #pragma unroll
    for (int reg = 0; reg < 8; ++reg) {
        int ch = (reg & 3) + 8 * (reg >> 2) + 4 * kb;
        cinit[reg] = bias[ch] * (float)CNT[ch];
    }
    #pragma unroll
    for (int reg = 8; reg < 16; ++reg) cinit[reg] = 0.f;

    const int gxL = 32 * wv + nn;              // always < 252
    const int gxH = 128 + 32 * wv + nn;        // may exceed 251
    const bool okH = gxH < 252;
    const int pbL = 3 * kb * PLANE_DW + (gxL >> 1);
    const int pbH = 3 * kb * PLANE_DW + (gxH >> 1);
    const bool oddL = (gxL >> 1) & 1;
    const bool oddH = (gxH >> 1) & 1;
    const unsigned shb = (unsigned)((nn & 1) * 16);

    auto loadf = [&](int dw, bool odd) -> f16x8 {
        int d0 = dw & ~1;
        uint2 r0 = *reinterpret_cast<const uint2*>(&s_lds[d0]);
        uint2 r1 = *reinterpret_cast<const uint2*>(&s_lds[d0 + 2]);
        uint2 r2 = *reinterpret_cast<const uint2*>(&s_lds[d0 + 4]);
        unsigned e0 = odd ? r0.y : r0.x;
        unsigned e1 = odd ? r1.x : r0.y;
        unsigned e2 = odd ? r1.y : r1.x;
        unsigned e3 = odd ? r2.x : r1.y;
        unsigned e4 = odd ? r2.y : r2.x;
        unsigned o0 = (unsigned)((((unsigned long long)e1 << 32) | e0) >> shb);
        unsigned o1 = (unsigned)((((unsigned long long)e2 << 32) | e1) >> shb);
        unsigned o2 = (unsigned)((((unsigned long long)e3 << 32) | e2) >> shb);
        unsigned o3 = (unsigned)((((unsigned long long)e4 << 32) | e3) >> shb);
        return u4_to_h8(make_uint4(o0, o1, o2, o3));
    };

    // prologue: rows 0..4 x 3 planes x 2 strips
    f16x8 L00 = loadf(pbL + 0*PITCH_DW, oddL), L01 = loadf(pbL + 1*PITCH_DW, oddL),
          L02 = loadf(pbL + 2*PITCH_DW, oddL), L03 = loadf(pbL + 3*PITCH_DW, oddL),
          L04 = loadf(pbL + 4*PITCH_DW, oddL);
    f16x8 L10 = loadf(pbL + PLANE_DW + 0*PITCH_DW, oddL), L11 = loadf(pbL + PLANE_DW + 1*PITCH_DW, oddL),
          L12 = loadf(pbL + PLANE_DW + 2*PITCH_DW, oddL), L13 = loadf(pbL + PLANE_DW + 3*PITCH_DW, oddL),
          L14 = loadf(pbL + PLANE_DW + 4*PITCH_DW, oddL);
    f16x8 L20 = loadf(pbL + 2*PLANE_DW + 0*PITCH_DW, oddL), L21 = loadf(pbL + 2*PLANE_DW + 1*PITCH_DW, oddL),
          L22 = loadf(pbL + 2*PLANE_DW + 2*PITCH_DW, oddL), L23 = loadf(pbL + 2*PLANE_DW + 3*PITCH_DW, oddL),
          L24 = loadf(pbL + 2*PLANE_DW + 4*PITCH_DW, oddL);
    f16x8 H00 = loadf(pbH + 0*PITCH_DW, oddH), H01 = loadf(pbH + 1*PITCH_DW, oddH),
          H02 = loadf(pbH + 2*PITCH_DW, oddH), H03 = loadf(pbH + 3*PITCH_DW, oddH),
          H04 = loadf(pbH + 4*PITCH_DW, oddH);
    f16x8 H10 = loadf(pbH + PLANE_DW + 0*PITCH_DW, oddH), H11 = loadf(pbH + PLANE_DW + 1*PITCH_DW, oddH),
          H12 = loadf(pbH + PLANE_DW + 2*PITCH_DW, oddH), H13 = loadf(pbH + PLANE_DW + 3*PITCH_DW, oddH),
          H14 = loadf(pbH + PLANE_DW + 4*PITCH_DW, oddH);
    f16x8 H20 = loadf(pbH + 2*PLANE_DW + 0*PITCH_DW, oddH), H21 = loadf(pbH + 2*PLANE_DW + 1*PITCH_DW, oddH),
          H22 = loadf(pbH + 2*PLANE_DW + 2*PITCH_DW, oddH), H23 = loadf(pbH + 2*PLANE_DW + 3*PITCH_DW, oddH),
          H24 = loadf(pbH + 2*PLANE_DW + 4*PITCH_DW, oddH);
    int rowOff = 5 * PITCH_DW;

    float* const opL = out + (size_t)n * 16 * 63504 + (size_t)(4 * kb) * 63504 + gxL;
    float* const opH = out + (size_t)n * 16 * 63504 + (size_t)(4 * kb) * 63504 + gxH;
    int yoff = Y0 * 252;

#define MFMA32(a, b, c) __builtin_amdgcn_mfma_f32_32x32x16_f16(a, b, c, 0, 0, 0)

#define STRIP(f00,f01,f02,f03,f04, f10,f11,f12,f13,f14, f20,f21,f22,f23,f24, pb, od, opg, ok) \
    {                                                                          \
        f32x16 acc = cinit;                                                    \
        acc = MFMA32(W[0],  f00, acc);  acc = MFMA32(W[1],  f01, acc);         \
        acc = MFMA32(W[2],  f02, acc);  acc = MFMA32(W[3],  f03, acc);         \
        acc = MFMA32(W[4],  f04, acc);                                         \
        acc = MFMA32(W[5],  f10, acc);  acc = MFMA32(W[6],  f11, acc);         \
        acc = MFMA32(W[7],  f12, acc);  acc = MFMA32(W[8],  f13, acc);         \
        acc = MFMA32(W[9],  f14, acc);                                         \
        acc = MFMA32(W[10], f20, acc);  acc = MFMA32(W[11], f21, acc);         \
        acc = MFMA32(W[12], f22, acc);  acc = MFMA32(W[13], f23, acc);         \
        acc = MFMA32(W[14], f24, acc);                                         \
        if (ok) {                                                              \
            opg[yoff +  0 * 63504] = acc[0];                                   \
            opg[yoff +  1 * 63504] = acc[1];                                   \
            opg[yoff +  2 * 63504] = acc[2];                                   \
            opg[yoff +  3 * 63504] = acc[3];                                   \
            opg[yoff +  8 * 63504] = acc[4];                                   \
            opg[yoff +  9 * 63504] = acc[5];                                   \
            opg[yoff + 10 * 63504] = acc[6];                                   \
            opg[yoff + 11 * 63504] = acc[7];                                   \
        }                                                                      \
        f00 = loadf(pb + rowOff, od);                                          \
        f10 = loadf(pb + PLANE_DW + rowOff, od);                               \
        f20 = loadf(pb + 2 * PLANE_DW + rowOff, od);                           \
    }

#define PHASE(r0,r1,r2,r3,r4)                                                          \
    STRIP(L0##r0,L0##r1,L0##r2,L0##r3,L0##r4, L1##r0,L1##r1,L1##r2,L1##r3,L1##r4,      \
          L2##r0,L2##r1,L2##r2,L2##r3,L2##r4, pbL, oddL, opL, true)                    \
    STRIP(H0##r0,H0##r1,H0##r2,H0##r3,H0##r4, H1##r0,H1##r1,H1##r2,H1##r3,H1##r4,      \
          H2##r0,H2##r1,H2##r2,H2##r3,H2##r4, pbH, oddH, opH, okH)                     \
    rowOff += PITCH_DW; yoff += 252;

    PHASE(0,1,2,3,4)
    PHASE(1,2,3,4,0)
    PHASE(2,3,4,0,1)
    PHASE(3,4,0,1,2)
    PHASE(4,0,1,2,3)
    PHASE(0,1,2,3,4)
    PHASE(1,2,3,4,0)
    PHASE(2,3,4,0,1)
    PHASE(3,4,0,1,2)
    PHASE(4,0,1,2,3)
    PHASE(0,1,2,3,4)
    PHASE(1,2,3,4,0)
#undef PHASE
#undef STRIP
#undef MFMA32
}

extern "C" void kernel_launch(void* const* d_in, const int* in_sizes, int n_in,
                              void* d_out, int out_size, void* d_ws, size_t ws_size,
                              hipStream_t stream) {
    const float* x    = (const float*)d_in[0];  // (64,6,256,256)
    const float* w    = (const float*)d_in[1];  // (10,6,5,5)
    const float* bias = (const float*)d_in[2];  // (1,16,1,1)
    float* out = (float*)d_out;                 // (64,16,252,252)
    unsigned short* Wp = (unsigned short*)d_ws; // 7680 halves (15 KB) A panel

    hipLaunchKernelGGL(prep_A, dim3(30), dim3(256), 0, stream, w, Wp);
    hipLaunchKernelGGL(c3_mfma, dim3(1344), dim3(256), 0, stream, x, Wp, bias, out);
}